// Round 10
// baseline (884.614 us; speedup 1.0000x reference)
//
#include <hip/hip_runtime.h>

#define T_LEN 2048
#define HID   25
#define LOG2E 1.4426950408889634f

__device__ __forceinline__ float fast_rcp(float x) { return __builtin_amdgcn_rcpf(x); }
__device__ __forceinline__ float fast_exp2(float x) { return __builtin_amdgcn_exp2f(x); }

// R10 = R9 layout with the LDS h-exchange replaced by v_readlane SGPR
// broadcast. One chain per 64-lane wave: lower lane u owns rows i_u,g_u;
// upper lane 32+u owns f_u,o_u (50 fp32 weights/lane). h is wave-uniform, so
// after the upper half computes h_u, 25 v_readlane_b32 (lane 32+k -> SGPR)
// distribute it; v_fma_f32 takes the SGPR directly as its one scalar operand.
// This removes ~7 ds_read + 1 ds_write per wave-step: R5/R9 both plateaued at
// ~815 cyc/step with 8 waves/CU x ~9 DS ops on the single per-CU DS pipe.
// 2048 waves = 2 waves/SIMD hides the trans-chain + readlane latency (m114).
// amdgpu_waves_per_eu(2,2): 256-VGPR budget, no AGPR demotion (R8 lesson);
// SGPR budget ~102 holds sh[25] + overhead.
// sigmoid/tanh in exp2 domain (weights pre-scaled by -log2e / +2log2e);
// per-gate fma order identical to R5/R8/R9 (two accumulators, k=0..11 /
// 12..24, all passed at exactly 1.953e-3).

__global__ __attribute__((amdgpu_flat_work_group_size(256, 256),
                          amdgpu_waves_per_eu(2, 2)))
void lstm_fused(
    const float* __restrict__ x,        // [B, T, 1]
    const float* __restrict__ w_ih,     // [100, 1]
    const float* __restrict__ w_hh,     // [100, 25]
    const float* __restrict__ b_ih,     // [100]
    const float* __restrict__ b_hh,     // [100]
    const float* __restrict__ w_dense,  // [1, 25]
    const float* __restrict__ b_dense,  // [1]
    float* __restrict__ out)            // [B, T, 1]
{
    const int tid  = threadIdx.x;
    const int L    = tid & 63;           // lane in wave
    const int u    = L & 31;             // hidden unit / t'-slot for this lane
    const bool up  = L >= 32;            // upper half: f/o rows, owns c and h
    const int cl   = tid >> 6;           // wave (= chain) index in block, 0..3
    const int b    = blockIdx.x * 4 + cl;
    const bool act = u < HID;

    // h history for batched y only (off the recurrence critical path):
    // 32 steps x 33 floats, stride 33 keeps the lane=u reads conflict-free.
    __shared__ float hist[4][32][33];

    const int rowA = up ? (HID + u)     : u;              // f-row : i-row
    const int rowB = up ? (3 * HID + u) : (2 * HID + u);  // o-row : g-row
    const float sclA = -LOG2E;                            // sigmoid gates
    const float sclB = up ? -LOG2E : 2.f * LOG2E;         // o: sigmoid, g: tanh

    // ---- 50 recurrent fp32 weights per lane, pre-scaled into exp2 domain ----
    float wAv[HID], wBv[HID];
#pragma unroll
    for (int k = 0; k < HID; ++k) {
        wAv[k] = act ? sclA * w_hh[rowA * HID + k] : 0.f;
        wBv[k] = act ? sclB * w_hh[rowB * HID + k] : 0.f;
    }
    const float bA  = act ? sclA * (b_ih[rowA] + b_hh[rowA]) : 0.f;
    const float bB  = act ? sclB * (b_ih[rowB] + b_hh[rowB]) : 0.f;
    const float wxA = act ? sclA * w_ih[rowA] : 0.f;
    const float wxB = act ? sclB * w_ih[rowB] : 0.f;
    const float bd  = b_dense[0];
    // tB = fmaf(-tmul, sB, 1): tanh(g) on lower half, exactly 1.0 on upper
    const float tmul = up ? 0.f : 2.f;

    // dense weights for the batched y: lower half sums u'=0..12, upper 13..24
    const int u0 = up ? 13 : 0;
    float wdv[13];
#pragma unroll
    for (int i = 0; i < 13; ++i) wdv[i] = (u0 + i < HID) ? w_dense[u0 + i] : 0.f;

    const float4* __restrict__ xp = (const float4*)(x + (size_t)b * T_LEN);
    float* __restrict__ orow = out + (size_t)b * T_LEN;

    // wave-uniform h state (SGPR-resident via readlane); h0 = 0
    float sh[HID];
#pragma unroll
    for (int k = 0; k < HID; ++k) sh[k] = 0.f;

    float c = 0.f;        // real on upper half, bounded junk on lower
    float4 xcur = xp[0];

    for (int it = 0; it < T_LEN / 4; ++it) {
        const int nx = (it + 1 < T_LEN / 4) ? it + 1 : it;
        float4 xnext = xp[nx];  // issued ~4 steps ahead of use
        float xs[4] = {xcur.x, xcur.y, xcur.z, xcur.w};

#pragma unroll
        for (int s = 0; s < 4; ++s) {
            const float xv = xs[s];
            const int t = 4 * it + s;

            // gate pre-activations, two accumulators per gate (k=0..11 /
            // 12..24) -- fma order identical to R5/R8/R9 (1.953e-3).
            // sh[k] is an SGPR: v_fma_f32's single allowed scalar operand.
            float aA0 = fmaf(xv, wxA, bA), aA1 = 0.f;
            float aB0 = fmaf(xv, wxB, bB), aB1 = 0.f;
#pragma unroll
            for (int k = 0; k < 12; ++k) {
                aA0 = fmaf(sh[k], wAv[k], aA0);
                aB0 = fmaf(sh[k], wBv[k], aB0);
            }
#pragma unroll
            for (int k = 12; k < HID; ++k) {
                aA1 = fmaf(sh[k], wAv[k], aA1);
                aB1 = fmaf(sh[k], wBv[k], aB1);
            }
            const float aA = aA0 + aA1;     // lower: i-preact, upper: f-preact
            const float aB = aB0 + aB1;     // lower: g-preact, upper: o-preact

            const float sA = fast_rcp(1.f + fast_exp2(aA));  // sig(i) / sig(f)
            const float sB = fast_rcp(1.f + fast_exp2(aB));  // g-aux  / sig(o)
            const float tB = fmaf(-tmul, sB, 1.f);           // tanh(g) / 1.0
            const float vv = sA * tB;                        // i*tanh(g) / sig(f)
            const float ov = __shfl_xor(vv, 32, 64);         // swap halves

            c = fmaf(vv, c, ov);             // upper: f*c + i*g   (lower: junk)
            const float tC = fmaf(-2.f, fast_rcp(1.f + fast_exp2(2.f * LOG2E * c)), 1.f);
            const float hn = sB * tC;        // upper: o*tanh(c)   (lower: junk)

            // y history (only DS op in the hot path; off the critical path)
            if (up && act) hist[cl][t & 31][u] = hn;

            // broadcast h_t: 25 v_readlane (lane 32+k, exec-ignoring) -> SGPRs.
            // Bit-exact same values the LDS round trip delivered; no memory,
            // no ordering hazard, no DS-pipe traffic.
            {
                const int hb = __builtin_bit_cast(int, hn);
#pragma unroll
                for (int k = 0; k < HID; ++k)
                    sh[k] = __builtin_bit_cast(float,
                              __builtin_amdgcn_readlane(hb, 32 + k));
            }

            // batched y: every 32 steps lane L computes its half-sum of
            // y[t0 + u]; shfl_xor(32) combines halves; lower half stores.
            if ((t & 31) == 31) {
                const float* hrow = &hist[cl][u][0];   // row for t' = t0 + u
                float ys = 0.f;
#pragma unroll
                for (int i = 0; i < 13; ++i)
                    ys = fmaf(hrow[u0 + i], wdv[i], ys);   // [25] pad reads 0*0
                ys += __shfl_xor(ys, 32, 64);
                if (!up) orow[(t & ~31) + u] = ys + bd;    // 128 B coalesced
            }
        }
        xcur = xnext;
    }
}

extern "C" void kernel_launch(void* const* d_in, const int* in_sizes, int n_in,
                              void* d_out, int out_size, void* d_ws, size_t ws_size,
                              hipStream_t stream) {
    const float* x       = (const float*)d_in[0];
    const float* w_ih    = (const float*)d_in[1];
    const float* w_hh    = (const float*)d_in[2];
    const float* b_ih    = (const float*)d_in[3];
    const float* b_hh    = (const float*)d_in[4];
    const float* w_dense = (const float*)d_in[5];
    const float* b_dense = (const float*)d_in[6];
    float* out = (float*)d_out;

    // 2048 chains, one per 64-lane wave: 512 blocks x 256 threads
    // -> 2 blocks/CU, 8 waves/CU = 2 waves/SIMD (sibling-wave latency hiding).
    lstm_fused<<<dim3(512), dim3(256), 0, stream>>>(x, w_ih, w_hh, b_ih, b_hh,
                                                    w_dense, b_dense, out);
}

// Round 11
// 545.015 us; speedup vs baseline: 1.6231x; 1.6231x over previous
//
#include <hip/hip_runtime.h>

#define T_LEN 2048
#define HID   25
#define LOG2E 1.4426950408889634f

// may_alias vector for the LDS h-row readback (written as scalar float):
// without it, TBAA licenses hoisting the read above the publish (R3/R7 bug).
typedef float vf4 __attribute__((vector_size(16), may_alias));
typedef float f2  __attribute__((ext_vector_type(2)));

__device__ __forceinline__ float fast_rcp(float x) { return __builtin_amdgcn_rcpf(x); }
__device__ __forceinline__ float fast_exp2(float x) { return __builtin_amdgcn_exp2f(x); }

// R11 = R8 (620 us champion) + v_pk_fma_f32 dot products.
// One chain per 32-lane half-wave; lane u owns ALL FOUR gate rows of unit u.
// 1 wave/SIMD chip-wide; amdgpu_waves_per_eu(1,1) -> full VGPR budget, no
// AGPR demotion (R8 lesson). h exchange via LDS broadcast row (readlane is
// empirically worse twice: R6/R10 both +200 cyc of v_mov overhead).
// NEW: gate dots use v_pk_fma_f32 with lanes paired (k, k+12): acc.x replays
// the k=0..11 accumulator, acc.y the k=12..23 one, h24 scalar last ->
// bit-identical summation order to R5/R8/R9 (all passed at 1.953e-3), at
// half the issue slots. The LDS h row is stored INTERLEAVED
// [h0,h12,h1,h13,...,h11,h23,h24] so the b128 readback yields register-
// aligned 64-bit (h_k, h_{k+12}) pairs with no repack movs.
// sigmoid/tanh in exp2 domain (weights pre-scaled by -log2e / +2log2e).

__global__ __attribute__((amdgpu_flat_work_group_size(256, 256),
                          amdgpu_waves_per_eu(1, 1)))
void lstm_fused(
    const float* __restrict__ x,        // [B, T, 1]
    const float* __restrict__ w_ih,     // [100, 1]
    const float* __restrict__ w_hh,     // [100, 25]
    const float* __restrict__ b_ih,     // [100]
    const float* __restrict__ b_hh,     // [100]
    const float* __restrict__ w_dense,  // [1, 25]
    const float* __restrict__ b_dense,  // [1]
    float* __restrict__ out)            // [B, T, 1]
{
    const int tid  = threadIdx.x;
    const int u    = tid & 31;           // hidden unit / t'-slot owned by lane
    const int cb   = tid >> 5;           // chain index in block, 0..7
    const int b    = blockIdx.x * 8 + cb;
    const bool act = u < HID;

    // Interleaved broadcast row per chain: slot 2m = h_m, 2m+1 = h_{m+12}
    // (m=0..11), slot 24 = h_24, slots 25..31 = junk-lane parking (never read).
    __shared__ __align__(16) float hbuf[8][32];
    // h history for batched y: 32 steps x 33 floats (stride 33: the lane=u
    // strided read in the y phase is conflict-free).
    __shared__ float hist[8][32][33];

    const float si = -LOG2E, sg = 2.f * LOG2E;

    // ---- recurrent weights as (k, k+12) pairs, pre-scaled into exp2 domain ----
    f2 wI2[12], wF2[12], wG2[12], wO2[12];
#pragma unroll
    for (int m = 0; m < 12; ++m) {
        wI2[m] = act ? f2{si * w_hh[u * HID + m],             si * w_hh[u * HID + m + 12]}             : f2{0.f, 0.f};
        wF2[m] = act ? f2{si * w_hh[(HID + u) * HID + m],     si * w_hh[(HID + u) * HID + m + 12]}     : f2{0.f, 0.f};
        wG2[m] = act ? f2{sg * w_hh[(2 * HID + u) * HID + m], sg * w_hh[(2 * HID + u) * HID + m + 12]} : f2{0.f, 0.f};
        wO2[m] = act ? f2{si * w_hh[(3 * HID + u) * HID + m], si * w_hh[(3 * HID + u) * HID + m + 12]} : f2{0.f, 0.f};
    }
    const float wI24 = act ? si * w_hh[u * HID + 24]             : 0.f;
    const float wF24 = act ? si * w_hh[(HID + u) * HID + 24]     : 0.f;
    const float wG24 = act ? sg * w_hh[(2 * HID + u) * HID + 24] : 0.f;
    const float wO24 = act ? si * w_hh[(3 * HID + u) * HID + 24] : 0.f;

    const float bI  = act ? si * (b_ih[u] + b_hh[u]) : 0.f;
    const float bF  = act ? si * (b_ih[HID + u] + b_hh[HID + u]) : 0.f;
    const float bG  = act ? sg * (b_ih[2 * HID + u] + b_hh[2 * HID + u]) : 0.f;
    const float bO  = act ? si * (b_ih[3 * HID + u] + b_hh[3 * HID + u]) : 0.f;
    const float wxI = act ? si * w_ih[u] : 0.f;
    const float wxF = act ? si * w_ih[HID + u] : 0.f;
    const float wxG = act ? sg * w_ih[2 * HID + u] : 0.f;
    const float wxO = act ? si * w_ih[3 * HID + u] : 0.f;
    const float bd  = b_dense[0];

    // dense weights (wave-uniform loads -> SGPRs)
    float wdv[HID];
#pragma unroll
    for (int i = 0; i < HID; ++i) wdv[i] = w_dense[i];

    // h0 = 0 (all 32 slots)
    hbuf[cb][u] = 0.f;

    // interleaved publish slot: bijection lane->slot, conflict-free
    const int slot = (u < 12) ? 2 * u : (u < 24) ? 2 * u - 23 : u;
    float* hwr = &hbuf[cb][slot];
    const vf4* r4 = (const vf4*)&hbuf[cb][0];
    const float* hbF = &hbuf[cb][0];

    const float4* __restrict__ xp = (const float4*)(x + (size_t)b * T_LEN);
    float* __restrict__ orow = out + (size_t)b * T_LEN;

    // h state as 12 register-aligned pairs (h_m, h_{m+12}) + h24
    f2 hp[12];
#pragma unroll
    for (int m = 0; m < 12; ++m) hp[m] = f2{0.f, 0.f};
    float h24 = 0.f;

    float c = 0.f;
    float4 xcur = xp[0];

    for (int it = 0; it < T_LEN / 4; ++it) {
        const int nx = (it + 1 < T_LEN / 4) ? it + 1 : it;
        float4 xnext = xp[nx];  // issued ~4 steps ahead of use
        float xs[4] = {xcur.x, xcur.y, xcur.z, xcur.w};

#pragma unroll
        for (int s = 0; s < 4; ++s) {
            const float xv = xs[s];
            const int t = 4 * it + s;

            // four gate pre-activations via v_pk_fma_f32; acc.x = k=0..11
            // accumulator, acc.y = k=12..23; h24 scalar-fma last; final
            // add acc.x + acc.y -- bit-identical order to R8.
            f2 accI = f2{fmaf(xv, wxI, bI), 0.f};
            f2 accF = f2{fmaf(xv, wxF, bF), 0.f};
            f2 accG = f2{fmaf(xv, wxG, bG), 0.f};
            f2 accO = f2{fmaf(xv, wxO, bO), 0.f};
#pragma unroll
            for (int m = 0; m < 12; ++m) {
                const f2 h = hp[m];
                accI = __builtin_elementwise_fma(h, wI2[m], accI);
                accF = __builtin_elementwise_fma(h, wF2[m], accF);
                accG = __builtin_elementwise_fma(h, wG2[m], accG);
                accO = __builtin_elementwise_fma(h, wO2[m], accO);
            }
            const float aI = accI.x + fmaf(h24, wI24, accI.y);
            const float aF = accF.x + fmaf(h24, wF24, accF.y);
            const float aG = accG.x + fmaf(h24, wG24, accG.y);
            const float aO = accO.x + fmaf(h24, wO24, accO.y);

            const float sI = fast_rcp(1.f + fast_exp2(aI));          // sig(i)
            const float sF = fast_rcp(1.f + fast_exp2(aF));          // sig(f)
            const float sO = fast_rcp(1.f + fast_exp2(aO));          // sig(o)
            const float tG = fmaf(-2.f, fast_rcp(1.f + fast_exp2(aG)), 1.f); // tanh(g)

            c = fmaf(sF, c, sI * tG);
            const float tC = fmaf(-2.f, fast_rcp(1.f + fast_exp2(2.f * LOG2E * c)), 1.f);
            const float hn = sO * tC;

            // ---- ordered publish -> readback (fences compile-time only;
            // same-wave DS ops execute in order on HW) ----
            *hwr = hn;                       // interleaved slot (bijection)
            hist[cb][t & 31][u] = hn;        // all 32 lanes, slots 0..31 of 33
            __asm__ __volatile__("" ::: "memory");
            {
                vf4 a0 = r4[0], a1 = r4[1], a2 = r4[2];
                vf4 a3 = r4[3], a4 = r4[4], a5 = r4[5];
                hp[0]  = f2{a0[0], a0[1]}; hp[1]  = f2{a0[2], a0[3]};
                hp[2]  = f2{a1[0], a1[1]}; hp[3]  = f2{a1[2], a1[3]};
                hp[4]  = f2{a2[0], a2[1]}; hp[5]  = f2{a2[2], a2[3]};
                hp[6]  = f2{a3[0], a3[1]}; hp[7]  = f2{a3[2], a3[3]};
                hp[8]  = f2{a4[0], a4[1]}; hp[9]  = f2{a4[2], a4[3]};
                hp[10] = f2{a5[0], a5[1]}; hp[11] = f2{a5[2], a5[3]};
                h24 = hbF[24];
            }
            __asm__ __volatile__("" ::: "memory");

            // batched y: every 32 steps lane u computes y[t0+u] (full 25-sum,
            // hist reads conflict-free by stride-33), all 32 lanes store.
            if ((t & 31) == 31) {
                const float* hrow = &hist[cb][u][0];   // row for t' = t0 + u
                float ys = 0.f;
#pragma unroll
                for (int i = 0; i < HID; ++i)
                    ys = fmaf(hrow[i], wdv[i], ys);
                orow[(t & ~31) + u] = ys + bd;         // 128 B coalesced
            }
        }
        xcur = xnext;
    }
}

extern "C" void kernel_launch(void* const* d_in, const int* in_sizes, int n_in,
                              void* d_out, int out_size, void* d_ws, size_t ws_size,
                              hipStream_t stream) {
    const float* x       = (const float*)d_in[0];
    const float* w_ih    = (const float*)d_in[1];
    const float* w_hh    = (const float*)d_in[2];
    const float* b_ih    = (const float*)d_in[3];
    const float* b_hh    = (const float*)d_in[4];
    const float* w_dense = (const float*)d_in[5];
    const float* b_dense = (const float*)d_in[6];
    float* out = (float*)d_out;

    // 2048 chains, one per 32-lane half-wave: 256 blocks x 256 threads
    // -> 1024 waves = 1 wave/SIMD chip-wide, 4 waves/CU.
    lstm_fused<<<dim3(256), dim3(256), 0, stream>>>(x, w_ih, w_hh, b_ih, b_hh,
                                                    w_dense, b_dense, out);
}